// Round 2
// baseline (7352.619 us; speedup 1.0000x reference)
//
#include <hip/hip_runtime.h>
#include <math.h>

#define B_   64
#define T_   256
#define NIN  128
#define NH   2048
#define NBLK 256
#define NTHR 256

typedef unsigned int  u32;
typedef unsigned char u8;
typedef unsigned long long u64;
typedef __attribute__((ext_vector_type(8))) short bf16x8;
typedef __attribute__((ext_vector_type(4))) float f32x4;

// LDS layout (dynamic, 103,936 B total)
#define OFF_AHI  0        // ushort [8][2056]  = 32,896 B   (A_hi, col-major, padded)
#define OFF_ALO  32896    // ushort [8][2056]  = 32,896 B   (A_lo)
#define OFF_SPK  65792    // u32    [64][65]   = 16,640 B   (spike bits, padded stride)
#define OFF_LUT  82432    // bf16x8 [256]      =  4,096 B   (byte -> 8 bf16 0/1)
#define OFF_CRED 86528    // float  [16][272]  = 17,408 B   (K-split partial C tiles)
#define SMEM_BYTES 103936
// init-phase overlay: float xS[64][132] = 33,792 B at offset 0 (dead before A load)

// ws layout: u32 cnt[512] @0 (2048 B) | u8 spkbuf0[64*256] @2048 | u8 spkbuf1 @18432

__device__ __forceinline__ unsigned short f2bf(float f) {
    u32 u = __float_as_uint(f);
    u32 r = (u + 0x7FFFu + ((u >> 16) & 1u)) >> 16;
    return (unsigned short)r;
}
__device__ __forceinline__ float bf2f(unsigned short h) {
    return __uint_as_float(((u32)h) << 16);
}

__device__ __forceinline__ void gbar(u32* slot, int tid) {
    __syncthreads();
    if (tid == 0) {
        __hip_atomic_fetch_add(slot, 1u, __ATOMIC_RELEASE, __HIP_MEMORY_SCOPE_AGENT);
        long g = 0;
        while (__hip_atomic_load(slot, __ATOMIC_ACQUIRE, __HIP_MEMORY_SCOPE_AGENT) < (u32)NBLK) {
            __builtin_amdgcn_s_sleep(2);
            if (++g > 2000000L) break;   // failsafe: terminate (visibly wrong) instead of hang
        }
    }
    __syncthreads();
}

__global__ __launch_bounds__(512) void zero_cnt(u32* cnt) { cnt[threadIdx.x] = 0u; }

__global__ __launch_bounds__(256, 1) void persist(
    const float* __restrict__ x,      // [B,T,NIN]
    const float* __restrict__ W_in,   // [NIN,NH]
    const float* __restrict__ A,      // [NH,NH]
    const float* __restrict__ bias,   // [NH]
    const float* __restrict__ mem0,   // [B,NH]
    float* __restrict__ out_mem,      // [B,T,NH]
    float* __restrict__ out_spk,      // [B,T,NH] (holds U_pre during init)
    u8* __restrict__ spkbuf,          // two 16 KB byte-mask buffers
    u32* __restrict__ cnt)            // 512 barrier slots (pre-zeroed)
{
    extern __shared__ char smem[];
    const int tid  = threadIdx.x;
    const int bid  = blockIdx.x;
    const int wave = tid >> 6;
    const int lane = tid & 63;
    const int c0   = bid * 8;

    unsigned short* AhiS = (unsigned short*)(smem + OFF_AHI);
    unsigned short* AloS = (unsigned short*)(smem + OFF_ALO);
    u32*            spkW = (u32*)(smem + OFF_SPK);
    unsigned short* lutS = (unsigned short*)(smem + OFF_LUT);
    const bf16x8*   lutV = (const bf16x8*)(smem + OFF_LUT);
    float*          credF = (float*)(smem + OFF_CRED);
    float*          xS   = (float*)(smem + OFF_AHI);   // overlay (init only)

    // ===================== INIT 1: U precompute (M-split: bt rows bid*64..+63) ==
    for (int idx = tid; idx < 64 * NIN; idx += NTHR) {
        int r = idx >> 7, k = idx & 127;
        xS[r * 132 + k] = x[(size_t)(bid * 64 + r) * NIN + k];
    }
    __syncthreads();
    for (int cg = 0; cg < 8; ++cg) {
        int col = cg * 256 + tid;
        float bcol = bias[col];
        for (int rb = 0; rb < 2; ++rb) {
            float acc[32];
#pragma unroll
            for (int r = 0; r < 32; ++r) acc[r] = 0.f;
            for (int kb = 0; kb < 4; ++kb) {
                float wreg[32];
#pragma unroll
                for (int kk = 0; kk < 32; ++kk)
                    wreg[kk] = W_in[(size_t)(kb * 32 + kk) * NH + col];
#pragma unroll 4
                for (int r = 0; r < 32; ++r) {
                    const f32x4* xv = (const f32x4*)(xS + (rb * 32 + r) * 132 + kb * 32);
                    float a = acc[r];
#pragma unroll
                    for (int q = 0; q < 8; ++q) {
                        f32x4 v = xv[q];
                        a += v.x * wreg[q * 4] + v.y * wreg[q * 4 + 1]
                           + v.z * wreg[q * 4 + 2] + v.w * wreg[q * 4 + 3];
                    }
                    acc[r] = a;
                }
            }
#pragma unroll 4
            for (int r = 0; r < 32; ++r)
                out_spk[(size_t)(bid * 64 + rb * 32 + r) * NH + col] = 0.5f * (acc[r] + bcol);
        }
    }
    __syncthreads();   // xS dead; region reused for A_hi/A_lo

    // ===================== INIT 2: A split-bf16 into LDS, LUT, spike buf0, mem ==
    for (int idx = tid; idx < 8 * NH; idx += NTHR) {
        int i = idx >> 3, c = idx & 7;
        float a = A[(size_t)i * NH + c0 + c];
        unsigned short hi = f2bf(a);
        float lo = a - bf2f(hi);
        AhiS[c * 2056 + i] = hi;
        AloS[c * 2056 + i] = f2bf(lo);
    }
#pragma unroll
    for (int j = 0; j < 8; ++j)
        lutS[tid * 8 + j] = ((tid >> j) & 1) ? (unsigned short)0x3F80 : (unsigned short)0;
    if (tid < B_) spkbuf[(size_t)tid * 256 + bid] = (u8)0;   // spike(t=-1) = 0

    const int c  = tid & 7;
    const int b0 = tid >> 3;        // 0..31
    const int b1 = b0 + 32;
    const int col = c0 + c;
    double m0 = (double)mem0[(size_t)b0 * NH + col];
    double m1 = (double)mem0[(size_t)b1 * NH + col];
    double s0p = 0.0, s1p = 0.0;

    gbar(cnt + 0, tid);

    // ===================== TIME LOOP ============================================
    const int n = lane & 15, quad = lane >> 4;
    const bf16x8 bz = {0, 0, 0, 0, 0, 0, 0, 0};

    for (int t = 0; t < T_; ++t) {
        const u8* spk_in  = spkbuf + ((t & 1) ? 16384 : 0);
        u8*       spk_out = spkbuf + ((t & 1) ? 0 : 16384);

        // stage spike bitmask -> LDS (agent loads bypass stale per-XCD L2)
        const u32* gin = (const u32*)spk_in;
        for (int idx = tid; idx < 4096; idx += NTHR) {
            u32 v = __hip_atomic_load(&gin[idx], __ATOMIC_RELAXED, __HIP_MEMORY_SCOPE_AGENT);
            spkW[(idx >> 6) * 65 + (idx & 63)] = v;
        }
        // prefetch U_pre (own data, read-once lines)
        float up0 = out_spk[(size_t)(b0 * T_ + t) * NH + col];
        float up1 = out_spk[(size_t)(b1 * T_ + t) * NH + col];
        __syncthreads();

        // MFMA: r = S @ (A_hi + A_lo), K-split across 4 waves
        f32x4 acc0 = {0.f, 0.f, 0.f, 0.f};
        f32x4 acc1 = acc0, acc2 = acc0, acc3 = acc0;
        const int sh = quad * 8;
        for (int ktl = 0; ktl < 16; ++ktl) {
            int kt = wave * 16 + ktl;
            bf16x8 bhi = bz, blo = bz;
            if (n < 8) {
                int eo = n * 2056 + kt * 32 + quad * 8;
                bhi = *(const bf16x8*)(AhiS + eo);
                blo = *(const bf16x8*)(AloS + eo);
            }
            u32 w0 = spkW[(n)      * 65 + kt];
            u32 w1 = spkW[(16 + n) * 65 + kt];
            u32 w2 = spkW[(32 + n) * 65 + kt];
            u32 w3 = spkW[(48 + n) * 65 + kt];
            bf16x8 a0 = lutV[(w0 >> sh) & 255u];
            bf16x8 a1 = lutV[(w1 >> sh) & 255u];
            bf16x8 a2 = lutV[(w2 >> sh) & 255u];
            bf16x8 a3 = lutV[(w3 >> sh) & 255u];
            acc0 = __builtin_amdgcn_mfma_f32_16x16x32_bf16(a0, bhi, acc0, 0, 0, 0);
            acc0 = __builtin_amdgcn_mfma_f32_16x16x32_bf16(a0, blo, acc0, 0, 0, 0);
            acc1 = __builtin_amdgcn_mfma_f32_16x16x32_bf16(a1, bhi, acc1, 0, 0, 0);
            acc1 = __builtin_amdgcn_mfma_f32_16x16x32_bf16(a1, blo, acc1, 0, 0, 0);
            acc2 = __builtin_amdgcn_mfma_f32_16x16x32_bf16(a2, bhi, acc2, 0, 0, 0);
            acc2 = __builtin_amdgcn_mfma_f32_16x16x32_bf16(a2, blo, acc2, 0, 0, 0);
            acc3 = __builtin_amdgcn_mfma_f32_16x16x32_bf16(a3, bhi, acc3, 0, 0, 0);
            acc3 = __builtin_amdgcn_mfma_f32_16x16x32_bf16(a3, blo, acc3, 0, 0, 0);
        }
        // write K-split partials: C/D layout col=lane&15, row=quad*4+reg
#pragma unroll
        for (int reg = 0; reg < 4; ++reg) {
            int row = quad * 4 + reg;
            credF[(wave * 4 + 0) * 272 + row * 17 + n] = acc0[reg];
            credF[(wave * 4 + 1) * 272 + row * 17 + n] = acc1[reg];
            credF[(wave * 4 + 2) * 272 + row * 17 + n] = acc2[reg];
            credF[(wave * 4 + 3) * 272 + row * 17 + n] = acc3[reg];
        }
        __syncthreads();

        // membrane update (fp64 state in registers)
        float r0 = 0.f, r1 = 0.f;
#pragma unroll
        for (int w = 0; w < 4; ++w) {
            r0 += credF[(w * 4 + (b0 >> 4)) * 272 + (b0 & 15) * 17 + c];
            r1 += credF[(w * 4 + (b1 >> 4)) * 272 + (b1 & 15) * 17 + c];
        }
        double y0 = tanh(0.5 * (double)r0 + (double)up0);
        double y1 = tanh(0.5 * (double)r1 + (double)up1);
        m0 = m0 * 0.5 - 0.5 * (1.0 - s0p) + y0;
        m1 = m1 * 0.5 - 0.5 * (1.0 - s1p) + y1;
        int sp0 = m0 > 0.5;
        int sp1 = m1 > 0.5;
        size_t o0 = (size_t)(b0 * T_ + t) * NH + col;
        size_t o1 = (size_t)(b1 * T_ + t) * NH + col;
        out_mem[o0] = (float)m0;
        out_mem[o1] = (float)m1;
        out_spk[o0] = sp0 ? 1.f : 0.f;
        out_spk[o1] = sp1 ? 1.f : 0.f;
        s0p = sp0 ? 1.0 : 0.0;
        s1p = sp1 ? 1.0 : 0.0;

        // publish spike bytes: block owns byte [b][bid] (8 cols = 1 byte)
        u64 bal0 = __ballot(sp0);
        u64 bal1 = __ballot(sp1);
        if ((lane & 7) == 0) {
            int i = lane >> 3;
            spk_out[(size_t)(wave * 8 + i) * 256 + bid]        = (u8)((bal0 >> (i * 8)) & 255u);
            spk_out[(size_t)(32 + wave * 8 + i) * 256 + bid]   = (u8)((bal1 >> (i * 8)) & 255u);
        }

        gbar(cnt + 1 + t, tid);
    }
}

extern "C" void kernel_launch(void* const* d_in, const int* in_sizes, int n_in,
                              void* d_out, int out_size, void* d_ws, size_t ws_size,
                              hipStream_t stream) {
    const float* x    = (const float*)d_in[0];
    const float* W_in = (const float*)d_in[1];
    const float* A    = (const float*)d_in[2];
    const float* bias = (const float*)d_in[3];
    const float* mem0 = (const float*)d_in[4];

    float* out_mem = (float*)d_out;
    float* out_spk = out_mem + (size_t)B_ * T_ * NH;

    char* ws = (char*)d_ws;
    u32* cnt    = (u32*)ws;
    u8*  spkbuf = (u8*)(ws + 2048);

    (void)hipFuncSetAttribute((const void*)persist,
                              hipFuncAttributeMaxDynamicSharedMemorySize, SMEM_BYTES);

    hipLaunchKernelGGL(zero_cnt, dim3(1), dim3(512), 0, stream, cnt);
    hipLaunchKernelGGL(persist, dim3(NBLK), dim3(NTHR), SMEM_BYTES, stream,
                       x, W_in, A, bias, mem0, out_mem, out_spk, spkbuf, cnt);
}

// Round 3
// 3085.402 us; speedup vs baseline: 2.3830x; 2.3830x over previous
//
#include <hip/hip_runtime.h>
#include <math.h>

#define B_   64
#define T_   256
#define NIN  128
#define NH   2048
#define NTHR 512

typedef unsigned int  u32;
typedef unsigned short u16;
typedef unsigned char u8;
typedef unsigned long long u64;
typedef __attribute__((ext_vector_type(8))) short bf16x8;
typedef __attribute__((ext_vector_type(4))) float f32x4;
typedef __attribute__((ext_vector_type(4))) u32   u32x4;

// persist LDS layout (dynamic, 148,992 B)
#define OFF_AHI  0         // u16 [16][2056]   = 65,792  (A_hi col-major, +8 pad)
#define OFF_ALO  65792     // u16 [16][2056]   = 65,792  (A_lo)
#define OFF_SPK  131584    // u16 [32][136]    =  8,704  (spike bits, 16/word)
#define OFF_CRED 140288    // f32 [8][16][17]  =  8,704  (K-split partials)
#define SMEM_BYTES 148992

// ws: u32 spkbuf[2][64][128] = 64 KB, zeroed each launch (tag 0 == step -1, spikes 0)

__device__ __forceinline__ u16 f2bf(float f) {
    u32 u = __float_as_uint(f);
    return (u16)((u + 0x7FFFu + ((u >> 16) & 1u)) >> 16);
}
__device__ __forceinline__ float bf2f(u16 h) { return __uint_as_float(((u32)h) << 16); }

// ============ U precompute: U_pre[b][t][col] = 0.5*(x[b,t]@W_in[:,col] + bias[col])
__global__ __launch_bounds__(256) void u_init(
    const float* __restrict__ x, const float* __restrict__ W_in,
    const float* __restrict__ bias, float* __restrict__ u_out)
{
    __shared__ float xS[64 * 132];
    const int tid = threadIdx.x, bid = blockIdx.x;
    for (int idx = tid; idx < 64 * NIN; idx += 256) {
        int r = idx >> 7, k = idx & 127;
        xS[r * 132 + k] = x[(size_t)(bid * 64 + r) * NIN + k];
    }
    __syncthreads();
    for (int cg = 0; cg < 8; ++cg) {
        int col = cg * 256 + tid;
        float bcol = bias[col];
        for (int rb = 0; rb < 2; ++rb) {
            float acc[32];
#pragma unroll
            for (int r = 0; r < 32; ++r) acc[r] = 0.f;
            for (int kb = 0; kb < 4; ++kb) {
                float wreg[32];
#pragma unroll
                for (int kk = 0; kk < 32; ++kk)
                    wreg[kk] = W_in[(size_t)(kb * 32 + kk) * NH + col];
#pragma unroll 4
                for (int r = 0; r < 32; ++r) {
                    const f32x4* xv = (const f32x4*)(xS + (rb * 32 + r) * 132 + kb * 32);
                    float a = acc[r];
#pragma unroll
                    for (int q = 0; q < 8; ++q) {
                        f32x4 v = xv[q];
                        a += v.x * wreg[q * 4] + v.y * wreg[q * 4 + 1]
                           + v.z * wreg[q * 4 + 2] + v.w * wreg[q * 4 + 3];
                    }
                    acc[r] = a;
                }
            }
#pragma unroll 4
            for (int r = 0; r < 32; ++r)
                u_out[(size_t)(bid * 64 + rb * 32 + r) * NH + col] = 0.5f * (acc[r] + bcol);
        }
    }
}

// ============ persistent per-(batch-group, col-block) recurrence, barrier-free
__global__ __launch_bounds__(NTHR, 2) void persist(
    const float* __restrict__ A,
    const float* __restrict__ mem0,
    float* __restrict__ out_mem,
    float* __restrict__ out_spk,   // holds U_pre until step t overwrites slot t
    u32* __restrict__ spkbuf)
{
    extern __shared__ char smem[];
    u16*   AhiS = (u16*)(smem + OFF_AHI);
    u16*   AloS = (u16*)(smem + OFF_ALO);
    u16*   spkS = (u16*)(smem + OFF_SPK);
    float* cred = (float*)(smem + OFF_CRED);

    const int tid = threadIdx.x;
    const int bid = blockIdx.x;      // 0..255
    const int cb  = bid & 127;       // col-block (16 cols)
    const int bg  = bid >> 7;        // batch group (32 batches)
    const int c0  = cb * 16;

    // A slice -> split-bf16 LDS (exact: a == hi + lo to fp32 round)
    for (int idx = tid; idx < NH * 16; idx += NTHR) {
        int i = idx >> 4, c = idx & 15;
        float a = A[(size_t)i * NH + c0 + c];
        u16 hi = f2bf(a);
        AhiS[c * 2056 + i] = hi;
        AloS[c * 2056 + i] = f2bf(a - bf2f(hi));
    }

    const int n   = tid & 15;        // col within block
    const int bl  = tid >> 4;        // local batch 0..31
    const int b   = bg * 32 + bl;
    const int col = c0 + n;
    double m = (double)mem0[(size_t)b * NH + col];
    double sprev = 0.0;

    const int lane = tid & 63, wave = tid >> 6;
    const int qn = lane & 15, quad = lane >> 4;
    const int mt = wave & 1;         // M-tile (batches mt*16..+16)
    const int kp = wave >> 1;        // K-partial 0..3
    const int bo = (quad & 1) * 8;

    __syncthreads();

    for (int t = 0; t < T_; ++t) {
        float up = out_spk[((size_t)b * T_ + t) * NH + col];   // own U_pre

        // ---- poll 8 tagged words (spikes of batch bl, col-groups (tid&15)*8..+8)
        const u32 tagexp = (u32)t;
        u32* src = spkbuf + ((t & 1) ? 8192 : 0) + b * 128 + (tid & 15) * 8;
        u32x4 pv = {0u, 0u, 0u, 0u};
        u32 got = 0;
        int guard = 0;
        while (got != 0xFFu) {
            u32 v[8];
#pragma unroll
            for (int j = 0; j < 8; ++j)
                if (!((got >> j) & 1))
                    v[j] = __hip_atomic_load(src + j, __ATOMIC_RELAXED, __HIP_MEMORY_SCOPE_AGENT);
#pragma unroll
            for (int j = 0; j < 8; ++j)
                if (!((got >> j) & 1) && (v[j] >> 16) == tagexp) {
                    pv[j >> 1] |= (v[j] & 0xFFFFu) << ((j & 1) * 16);
                    got |= (1u << j);
                }
            if (++guard > 50000) break;          // failsafe: visible failure, no hang
            if (guard > 8) __builtin_amdgcn_s_sleep(2);
        }
        *(bf16x8*)(spkS + bl * 136 + (tid & 15) * 8) = __builtin_bit_cast(bf16x8, pv);
        __syncthreads();

        // ---- r = S @ (A_hi + A_lo): 16x16x32 MFMA, 4-way K-split, 2 M-tiles
        f32x4 acc = {0.f, 0.f, 0.f, 0.f};
        const u16* bh = AhiS + qn * 2056 + quad * 8;
        const u16* blo_ = AloS + qn * 2056 + quad * 8;
        const u16* srow = spkS + (mt * 16 + qn) * 136 + (quad >> 1);
#pragma unroll 4
        for (int ktl = 0; ktl < 16; ++ktl) {
            int kt = kp * 16 + ktl;
            bf16x8 bhi = *(const bf16x8*)(bh + kt * 32);
            bf16x8 blo = *(const bf16x8*)(blo_ + kt * 32);
            u32 byte = ((u32)srow[kt * 2] >> bo) & 255u;
            u32x4 aw;
            aw.x = ((byte & 1u)   ? 0x3F80u : 0u) | ((byte & 2u)   ? 0x3F800000u : 0u);
            aw.y = ((byte & 4u)   ? 0x3F80u : 0u) | ((byte & 8u)   ? 0x3F800000u : 0u);
            aw.z = ((byte & 16u)  ? 0x3F80u : 0u) | ((byte & 32u)  ? 0x3F800000u : 0u);
            aw.w = ((byte & 64u)  ? 0x3F80u : 0u) | ((byte & 128u) ? 0x3F800000u : 0u);
            bf16x8 af = __builtin_bit_cast(bf16x8, aw);
            acc = __builtin_amdgcn_mfma_f32_16x16x32_bf16(af, bhi, acc, 0, 0, 0);
            acc = __builtin_amdgcn_mfma_f32_16x16x32_bf16(af, blo, acc, 0, 0, 0);
        }
#pragma unroll
        for (int reg = 0; reg < 4; ++reg)
            cred[((kp * 2 + mt) * 16 + quad * 4 + reg) * 17 + qn] = acc[reg];
        __syncthreads();

        // ---- reduce partials, fp64 membrane update, store, publish
        float r = 0.f;
#pragma unroll
        for (int p = 0; p < 4; ++p)
            r += cred[((p * 2 + (bl >> 4)) * 16 + (bl & 15)) * 17 + n];

        double y = tanh(0.5 * (double)r + (double)up);
        m = m * 0.5 - 0.5 * (1.0 - sprev) + y;
        int sp = m > 0.5;
        size_t o = ((size_t)b * T_ + t) * NH + col;
        out_mem[o] = (float)m;
        out_spk[o] = sp ? 1.f : 0.f;
        sprev = sp ? 1.0 : 0.0;

        u64 bal = __ballot(sp);
        if (n == 0) {
            u32 bits = (u32)((bal >> ((bl & 3) * 16)) & 0xFFFFull);
            u32 val = ((u32)(t + 1) << 16) | bits;
            u32* dst = spkbuf + ((t & 1) ? 0 : 8192) + b * 128 + cb;
            __hip_atomic_store(dst, val, __ATOMIC_RELAXED, __HIP_MEMORY_SCOPE_AGENT);
        }
        __syncthreads();   // spkS/cred reuse next step
    }
}

extern "C" void kernel_launch(void* const* d_in, const int* in_sizes, int n_in,
                              void* d_out, int out_size, void* d_ws, size_t ws_size,
                              hipStream_t stream) {
    const float* x    = (const float*)d_in[0];
    const float* W_in = (const float*)d_in[1];
    const float* A    = (const float*)d_in[2];
    const float* bias = (const float*)d_in[3];
    const float* mem0 = (const float*)d_in[4];

    float* out_mem = (float*)d_out;
    float* out_spk = out_mem + (size_t)B_ * T_ * NH;
    u32*   spkbuf  = (u32*)d_ws;

    (void)hipFuncSetAttribute((const void*)persist,
                              hipFuncAttributeMaxDynamicSharedMemorySize, SMEM_BYTES);

    hipMemsetAsync(spkbuf, 0, 2 * 64 * 128 * sizeof(u32), stream);
    hipLaunchKernelGGL(u_init, dim3(256), dim3(256), 0, stream, x, W_in, bias, out_spk);
    hipLaunchKernelGGL(persist, dim3(256), dim3(NTHR), SMEM_BYTES, stream,
                       A, mem0, out_mem, out_spk, spkbuf);
}